// Round 1
// baseline (201.211 us; speedup 1.0000x reference)
//
#include <hip/hip_runtime.h>
#include <hip/hip_bf16.h>
#include <math.h>

// S4D layer: y[b,h,l] = sum_{m<=l} K[h,m] u[b,h,l-m] + D[h] u[b,h,l]
// K[h,m] = Re( sum_n coef_{h,n} * lambda_{h,n}^m ),
// lambda = exp(step*A), coef = C * (lambda - 1) / A.
// Equivalent recurrence: s[l] = lambda*s[l-1] + u[l];  y[l] = Re(sum coef*s[l]) + D*u[l].
//
// Mapping: 4 sequences (b,h) per wave. Lane l: group g = l>>4 picks the sequence,
// sub = l&15 picks 4 states n = sub*4..sub*4+3. Per-step 16-lane reduce via DPP.

#define B_ 16
#define H_ 256
#define L_ 4096
#define N_ 64

template <int CTRL>
__device__ __forceinline__ float dpp_add(float x) {
    int v = __builtin_amdgcn_update_dpp(0, __float_as_int(x), CTRL, 0xF, 0xF, true);
    return x + __int_as_float(v);
}

__global__ __launch_bounds__(64) void s4d_scan_kernel(
    const float* __restrict__ u,
    const float* __restrict__ A_re,
    const float* __restrict__ A_im,
    const float* __restrict__ C,
    const float* __restrict__ D,
    const float* __restrict__ log_step,
    float* __restrict__ y)
{
    const int lane = threadIdx.x;   // 0..63
    const int g    = lane >> 4;     // which sequence of this wave's quad
    const int sub  = lane & 15;     // 16 lanes per sequence
    const int q    = blockIdx.x;    // quad id: sequences 4q..4q+3
    const int sid  = q * 4 + g;     // flat (b*H + h)
    const int h    = sid & (H_ - 1);

    // ---- per-lane parameters for n = sub*4 + k ----
    const int nbase = sub * 4;
    const float4 ar4 = *(const float4*)&A_re[h * N_ + nbase];
    const float4 ai4 = *(const float4*)&A_im[h * N_ + nbase];
    const float4 c01 = *(const float4*)&C[(h * N_ + nbase) * 2];
    const float4 c23 = *(const float4*)&C[(h * N_ + nbase) * 2 + 4];
    const float step = expf(log_step[h]);
    const float Dh   = D[h];

    float arv[4] = {ar4.x, ar4.y, ar4.z, ar4.w};
    float aiv[4] = {ai4.x, ai4.y, ai4.z, ai4.w};
    float crv[4] = {c01.x, c01.z, c23.x, c23.z};
    float civ[4] = {c01.y, c01.w, c23.y, c23.w};

    float lre[4], lim[4], cre[4], ncim[4];
#pragma unroll
    for (int k = 0; k < 4; ++k) {
        float are = fminf(arv[k], -1e-4f);       // clip(A_re, None, -1e-4)
        float aim = aiv[k];
        float dre = step * are, dim = step * aim;
        float er  = expf(dre);
        float lr  = er * cosf(dim);
        float li  = er * sinf(dim);
        lre[k] = lr; lim[k] = li;
        // (lambda - 1)/A  =  (lambda-1) * conj(A) / |A|^2
        float nre = lr - 1.0f, nim = li;
        float inv = 1.0f / (are * are + aim * aim);
        float qre = (nre * are + nim * aim) * inv;
        float qim = (nim * are - nre * aim) * inv;
        float cr = crv[k], ci = civ[k];
        cre[k]  = cr * qre - ci * qim;           // Re(coef)
        ncim[k] = -(cr * qim + ci * qre);        // -Im(coef)
    }

    float sre[4] = {0.f, 0.f, 0.f, 0.f};
    float smi[4] = {0.f, 0.f, 0.f, 0.f};

    __shared__ float ut[4][260];                 // 256 + 4 pad: row stride 1040B (16B-aligned, bank-skewed)

    const size_t ub = (size_t)(q * 4) * L_;
    float yreg = 0.f;

    for (int j0 = 0; j0 < L_; j0 += 256) {
        // ---- stage 256 steps of u for all 4 sequences (coalesced float4) ----
#pragma unroll
        for (int i = 0; i < 4; ++i) {
            float4 v = *(const float4*)&u[ub + (size_t)i * L_ + j0 + lane * 4];
            *(float4*)&ut[i][lane * 4] = v;
        }
        __syncthreads();

#pragma unroll 1
        for (int sb = 0; sb < 16; ++sb) {
            // broadcast-read this group's next 16 u values (conflict-free: groups hit distinct banks)
            float u16[16];
#pragma unroll
            for (int i = 0; i < 4; ++i) {
                float4 v = *(const float4*)&ut[g][sb * 16 + i * 4];
                u16[i * 4 + 0] = v.x; u16[i * 4 + 1] = v.y;
                u16[i * 4 + 2] = v.z; u16[i * 4 + 3] = v.w;
            }
#pragma unroll
            for (int t = 0; t < 16; ++t) {
                const float uj = u16[t];
                float z = 0.f;
#pragma unroll
                for (int k = 0; k < 4; ++k) {
                    float so = sre[k];
                    sre[k] = fmaf(lre[k], so, fmaf(-lim[k], smi[k], uj));
                    smi[k] = fmaf(lre[k], smi[k], lim[k] * so);
                    z = fmaf(cre[k], sre[k], z);
                    z = fmaf(ncim[k], smi[k], z);
                }
                // 16-lane butterfly sum, pure VALU (DPP)
                z = dpp_add<0xB1>(z);    // quad_perm xor 1
                z = dpp_add<0x4E>(z);    // quad_perm xor 2
                z = dpp_add<0x141>(z);   // row_half_mirror (xor 7 within 8)
                z = dpp_add<0x140>(z);   // row_mirror (xor 15 within 16)
                const float yv = fmaf(Dh, uj, z);
                yreg = (sub == t) ? yv : yreg;
            }
            y[(size_t)sid * L_ + j0 + sb * 16 + sub] = yreg;
        }
        __syncthreads();
    }
}

extern "C" void kernel_launch(void* const* d_in, const int* in_sizes, int n_in,
                              void* d_out, int out_size, void* d_ws, size_t ws_size,
                              hipStream_t stream) {
    const float* u        = (const float*)d_in[0];
    const float* A_re     = (const float*)d_in[1];
    const float* A_im     = (const float*)d_in[2];
    const float* C        = (const float*)d_in[3];
    const float* D        = (const float*)d_in[4];
    const float* log_step = (const float*)d_in[5];
    float* y = (float*)d_out;

    const int nquads = (B_ * H_) / 4;  // 1024 single-wave blocks
    s4d_scan_kernel<<<nquads, 64, 0, stream>>>(u, A_re, A_im, C, D, log_step, y);
}